// Round 6
// baseline (2216.358 us; speedup 1.0000x reference)
//
#include <hip/hip_runtime.h>
#include <math.h>

#define F_IN 128
#define HID  128
#define CDIM 64
#define BN_EPS 1e-5f
#define NBMAX 2048        // max buckets (N <= 131072)
#define BCHUNK 16384      // edges per bucketing block

typedef unsigned int u32;
typedef unsigned short u16;

// bf16 helpers (RNE)
__device__ __forceinline__ float bf_lo(u32 p) {
    u32 x = p << 16; return __builtin_bit_cast(float, x);
}
__device__ __forceinline__ float bf_hi(u32 p) {
    u32 x = p & 0xffff0000u; return __builtin_bit_cast(float, x);
}
__device__ __forceinline__ u16 f2bf(float f) {
    u32 x = __builtin_bit_cast(u32, f);
    return (u16)((x + 0x7fffu + ((x >> 16) & 1u)) >> 16);
}
__device__ __forceinline__ u32 pack2(float a, float b) {
    return (u32)f2bf(a) | ((u32)f2bf(b) << 16);   // lo = even col
}

// ---------------------------------------------------------------------------
// GEMM1: Y[N,128](bf16) = X[N,128](fp32) @ W[128,128](fp32).
// ---------------------------------------------------------------------------
__global__ __launch_bounds__(256) void gemm_xw1(const float* __restrict__ X,
                                                const float* __restrict__ W,
                                                u32* __restrict__ Yb, int N) {
    __shared__ float Wl[64][128];    // 32 KB
    __shared__ float xs[128][64];    // 32 KB
    const int cg = (threadIdx.x & 15) * 8;
    const int rg = (threadIdx.x >> 4) * 8;
    const int ntiles = (N + 127) >> 7;
    for (int tile = blockIdx.x; tile < ntiles; tile += gridDim.x) {
        const int row0 = tile << 7;
        float acc[8][8];
        #pragma unroll
        for (int i = 0; i < 8; ++i)
            #pragma unroll
            for (int j = 0; j < 8; ++j) acc[i][j] = 0.f;

        for (int kc = 0; kc < 128; kc += 64) {
            __syncthreads();
            for (int i = threadIdx.x; i < 2048; i += 256) {
                int kr = i >> 5, c = (i & 31) * 4;
                *(float4*)&Wl[kr][c] = *(const float4*)&W[(size_t)(kc + kr) * HID + c];
            }
            for (int i = threadIdx.x; i < 2048; i += 256) {
                int r = i >> 4, c = (i & 15) * 4;
                int gr = row0 + r;
                float4 v = make_float4(0.f, 0.f, 0.f, 0.f);
                if (gr < N) v = *(const float4*)&X[(size_t)gr * F_IN + kc + c];
                *(float4*)&xs[r][c] = v;
            }
            __syncthreads();
            #pragma unroll 2
            for (int k = 0; k < 64; k += 2) {
                float2 a[8];
                #pragma unroll
                for (int i = 0; i < 8; ++i) a[i] = *(float2*)&xs[rg + i][k];
                float4 b00 = *(float4*)&Wl[k][cg];
                float4 b01 = *(float4*)&Wl[k][cg + 4];
                float4 b10 = *(float4*)&Wl[k + 1][cg];
                float4 b11 = *(float4*)&Wl[k + 1][cg + 4];
                #pragma unroll
                for (int i = 0; i < 8; ++i) {
                    acc[i][0] = fmaf(a[i].x, b00.x, acc[i][0]);
                    acc[i][1] = fmaf(a[i].x, b00.y, acc[i][1]);
                    acc[i][2] = fmaf(a[i].x, b00.z, acc[i][2]);
                    acc[i][3] = fmaf(a[i].x, b00.w, acc[i][3]);
                    acc[i][4] = fmaf(a[i].x, b01.x, acc[i][4]);
                    acc[i][5] = fmaf(a[i].x, b01.y, acc[i][5]);
                    acc[i][6] = fmaf(a[i].x, b01.z, acc[i][6]);
                    acc[i][7] = fmaf(a[i].x, b01.w, acc[i][7]);
                    acc[i][0] = fmaf(a[i].y, b10.x, acc[i][0]);
                    acc[i][1] = fmaf(a[i].y, b10.y, acc[i][1]);
                    acc[i][2] = fmaf(a[i].y, b10.z, acc[i][2]);
                    acc[i][3] = fmaf(a[i].y, b10.w, acc[i][3]);
                    acc[i][4] = fmaf(a[i].y, b11.x, acc[i][4]);
                    acc[i][5] = fmaf(a[i].y, b11.y, acc[i][5]);
                    acc[i][6] = fmaf(a[i].y, b11.z, acc[i][6]);
                    acc[i][7] = fmaf(a[i].y, b11.w, acc[i][7]);
                }
            }
        }
        #pragma unroll
        for (int i = 0; i < 8; ++i) {
            int gr = row0 + rg + i;
            if (gr < N) {
                uint4 o;
                o.x = pack2(acc[i][0], acc[i][1]);
                o.y = pack2(acc[i][2], acc[i][3]);
                o.z = pack2(acc[i][4], acc[i][5]);
                o.w = pack2(acc[i][6], acc[i][7]);
                *(uint4*)&Yb[(size_t)gr * 64 + (cg >> 1)] = o;
            }
        }
    }
}

// ---------------------------------------------------------------------------
// GEMM2: Y[N,64](bf16) = H[N,128](bf16) @ W[128,64](fp32).
// ---------------------------------------------------------------------------
__global__ __launch_bounds__(256) void gemm_xw2(const u32* __restrict__ Hb,
                                                const float* __restrict__ W,
                                                u32* __restrict__ Yb, int N) {
    __shared__ float Wl[64][64];     // 16 KB
    __shared__ float xs[128][64];    // 32 KB
    const int cg = (threadIdx.x & 15) * 4;
    const int rg = (threadIdx.x >> 4) * 8;
    const int ntiles = (N + 127) >> 7;
    for (int tile = blockIdx.x; tile < ntiles; tile += gridDim.x) {
        const int row0 = tile << 7;
        float acc[8][4];
        #pragma unroll
        for (int i = 0; i < 8; ++i)
            #pragma unroll
            for (int j = 0; j < 4; ++j) acc[i][j] = 0.f;

        for (int kc = 0; kc < 128; kc += 64) {
            __syncthreads();
            for (int i = threadIdx.x; i < 1024; i += 256) {          // W chunk
                int kr = i >> 4, c = (i & 15) * 4;
                *(float4*)&Wl[kr][c] = *(const float4*)&W[(size_t)(kc + kr) * CDIM + c];
            }
            for (int i = threadIdx.x; i < 2048; i += 256) {          // H chunk
                int r = i >> 4, uc = (i & 15) * 2;
                int gr = row0 + r;
                float4 v = make_float4(0.f, 0.f, 0.f, 0.f);
                if (gr < N) {
                    uint2 p = *(const uint2*)&Hb[(size_t)gr * 64 + (kc >> 1) + uc];
                    v = make_float4(bf_lo(p.x), bf_hi(p.x), bf_lo(p.y), bf_hi(p.y));
                }
                *(float4*)&xs[r][uc * 2] = v;
            }
            __syncthreads();
            #pragma unroll 2
            for (int k = 0; k < 64; k += 2) {
                float2 a[8];
                #pragma unroll
                for (int i = 0; i < 8; ++i) a[i] = *(float2*)&xs[rg + i][k];
                float4 b0 = *(float4*)&Wl[k][cg];
                float4 b1 = *(float4*)&Wl[k + 1][cg];
                #pragma unroll
                for (int i = 0; i < 8; ++i) {
                    acc[i][0] = fmaf(a[i].x, b0.x, acc[i][0]);
                    acc[i][1] = fmaf(a[i].x, b0.y, acc[i][1]);
                    acc[i][2] = fmaf(a[i].x, b0.z, acc[i][2]);
                    acc[i][3] = fmaf(a[i].x, b0.w, acc[i][3]);
                    acc[i][0] = fmaf(a[i].y, b1.x, acc[i][0]);
                    acc[i][1] = fmaf(a[i].y, b1.y, acc[i][1]);
                    acc[i][2] = fmaf(a[i].y, b1.z, acc[i][2]);
                    acc[i][3] = fmaf(a[i].y, b1.w, acc[i][3]);
                }
            }
        }
        #pragma unroll
        for (int i = 0; i < 8; ++i) {
            int gr = row0 + rg + i;
            if (gr < N) {
                uint2 o;
                o.x = pack2(acc[i][0], acc[i][1]);
                o.y = pack2(acc[i][2], acc[i][3]);
                *(uint2*)&Yb[(size_t)gr * 32 + (cg >> 1)] = o;
            }
        }
    }
}

// ---------------------------------------------------------------------------
// Bucketing (dst >> 6). Step 1: per-block LDS histogram -> global counts.
// ---------------------------------------------------------------------------
__global__ __launch_bounds__(256) void bucket_hist(const int* __restrict__ dst,
                                                   int* __restrict__ gcount,
                                                   int E, int NB) {
    __shared__ int h[NBMAX];
    for (int i = threadIdx.x; i < NB; i += 256) h[i] = 0;
    __syncthreads();
    int base = blockIdx.x * BCHUNK;
    int lim = base + BCHUNK; if (lim > E) lim = E;
    for (int e = base + threadIdx.x; e < lim; e += 256)
        atomicAdd(&h[dst[e] >> 6], 1);
    __syncthreads();
    for (int i = threadIdx.x; i < NB; i += 256)
        if (h[i]) atomicAdd(&gcount[i], h[i]);
}

// Step 2: single-block exclusive scan of NB bucket counts -> boff, gcursor.
__global__ __launch_bounds__(256) void bucket_scan(const int* __restrict__ gcount,
                                                   int* __restrict__ boff,
                                                   int* __restrict__ gcursor,
                                                   int NB, int E) {
    __shared__ int sums[256];
    int v[8]; int tsum = 0;
    #pragma unroll
    for (int j = 0; j < 8; ++j) {
        int i = threadIdx.x * 8 + j;
        v[j] = (i < NB) ? gcount[i] : 0;
        tsum += v[j];
    }
    sums[threadIdx.x] = tsum; __syncthreads();
    for (int off = 1; off < 256; off <<= 1) {
        int t = (threadIdx.x >= off) ? sums[threadIdx.x - off] : 0;
        __syncthreads();
        sums[threadIdx.x] += t;
        __syncthreads();
    }
    int run = sums[threadIdx.x] - tsum;   // exclusive base
    #pragma unroll
    for (int j = 0; j < 8; ++j) {
        int i = threadIdx.x * 8 + j;
        if (i < NB) { boff[i] = run; gcursor[i] = run; run += v[j]; }
    }
    if (threadIdx.x == 0) boff[NB] = E;
}

// Step 3: ranked scatter into bucket-contiguous regions.
// meta = (row_local << 26) | src   (row_local = dst & 63, src < 2^26)
__global__ __launch_bounds__(256) void bucket_fill(const int* __restrict__ src,
                                                   const int* __restrict__ dst,
                                                   const float* __restrict__ w,
                                                   int* __restrict__ gcursor,
                                                   uint2* __restrict__ es,
                                                   int E, int NB) {
    __shared__ int h[NBMAX];
    for (int i = threadIdx.x; i < NB; i += 256) h[i] = 0;
    __syncthreads();
    int base = blockIdx.x * BCHUNK;
    int lim = base + BCHUNK; if (lim > E) lim = E;
    for (int e = base + threadIdx.x; e < lim; e += 256)
        atomicAdd(&h[dst[e] >> 6], 1);
    __syncthreads();
    // claim contiguous ranges; h[b] becomes this block's running cursor
    for (int i = threadIdx.x; i < NB; i += 256)
        if (h[i]) h[i] = atomicAdd(&gcursor[i], h[i]);
    __syncthreads();
    for (int e = base + threadIdx.x; e < lim; e += 256) {
        int d = dst[e];
        int pos = atomicAdd(&h[d >> 6], 1);
        uint2 pk;
        pk.x = ((u32)(d & 63) << 26) | (u32)src[e];
        pk.y = __builtin_bit_cast(u32, w[e]);
        es[pos] = pk;
    }
}

__global__ void bn_prep(const float* __restrict__ b1, const float* __restrict__ gamma,
                        const float* __restrict__ beta, const float* __restrict__ mean,
                        const float* __restrict__ var, float* __restrict__ scale,
                        float* __restrict__ shift) {
    int f = threadIdx.x;
    if (f < HID) {
        float sc = gamma[f] * rsqrtf(var[f] + BN_EPS);
        scale[f] = sc;
        shift[f] = beta[f] + sc * (b1[f] - mean[f]);
    }
}

// ---------------------------------------------------------------------------
// Layer-1 aggregation: block = bucket (64 rows x 128 cols). Edges streamed,
// accumulated via ds_add_f32 into split even/odd-col LDS arrays (2-way bank
// aliasing = free). Fused BN+ReLU bf16 writeback.
// ---------------------------------------------------------------------------
__global__ __launch_bounds__(256) void scatter1_kernel(
        const u32* __restrict__ XWb, const int* __restrict__ boff,
        const uint2* __restrict__ es, const float* __restrict__ scale,
        const float* __restrict__ shift, u32* __restrict__ Hb, int N) {
    __shared__ float lo[64 * 64];   // even cols: col 2f -> lo[row*64+f]
    __shared__ float hi[64 * 64];   // odd cols
    for (int i = threadIdx.x; i < 1024; i += 256) {
        *(float4*)&lo[i * 4] = make_float4(0.f, 0.f, 0.f, 0.f);
        *(float4*)&hi[i * 4] = make_float4(0.f, 0.f, 0.f, 0.f);
    }
    __syncthreads();
    const int b = blockIdx.x;
    const int row0 = b << 6;
    const int f = threadIdx.x & 63;
    const int wid = threadIdx.x >> 6;
    int beg = boff[b], end = boff[b + 1];
    for (int base = beg + wid * 64; base < end; base += 256) {
        int m = end - base; if (m > 64) m = 64;
        uint2 pk = (f < m) ? es[base + f] : make_uint2(0u, 0u);
        u32   me = pk.x;
        float we = __builtin_bit_cast(float, pk.y);
        for (int k = 0; k < m; ++k) {
            u32   mk = __shfl(me, k, 64);
            float wk = __shfl(we, k, 64);
            int row = (int)(mk >> 26);
            int s   = (int)(mk & 0x03FFFFFFu);
            u32 x = XWb[(size_t)s * 64 + f];
            atomicAdd(&lo[row * 64 + f], bf_lo(x) * wk);
            atomicAdd(&hi[row * 64 + f], bf_hi(x) * wk);
        }
    }
    __syncthreads();
    // epilogue: 4096 u32 outputs (64 rows x 64 packed cols)
    for (int i = threadIdx.x; i < 4096; i += 256) {
        int row = i >> 6, c = i & 63;
        int gr = row0 + row;
        if (gr < N) {
            float2 sc = *(const float2*)&scale[2 * c];
            float2 sh = *(const float2*)&shift[2 * c];
            float hx = fmaf(lo[i], sc.x, sh.x);
            float hy = fmaf(hi[i], sc.y, sh.y);
            hx = hx > 0.f ? hx : 0.f;
            hy = hy > 0.f ? hy : 0.f;
            Hb[(size_t)gr * 64 + c] = pack2(hx, hy);
        }
    }
}

// ---------------------------------------------------------------------------
// Layer-2 aggregation + full epilogue: block = bucket (64 rows x 64 cols).
// Two edges per wave-iteration (half-wave each). Epilogue: one wave per row,
// b2/delta-merge/log_softmax, direct store to outputs.
// ---------------------------------------------------------------------------
__global__ __launch_bounds__(256) void scatter2_final(
        const u32* __restrict__ XW2b, const int* __restrict__ boff,
        const uint2* __restrict__ es, const float* __restrict__ b2,
        const float* __restrict__ prev, const int* __restrict__ sens,
        const int* __restrict__ ins, float* __restrict__ out_lsm,
        float* __restrict__ out_emb, int N) {
    __shared__ float lo[64 * 32];
    __shared__ float hi[64 * 32];
    for (int i = threadIdx.x; i < 512; i += 256) {
        *(float4*)&lo[i * 4] = make_float4(0.f, 0.f, 0.f, 0.f);
        *(float4*)&hi[i * 4] = make_float4(0.f, 0.f, 0.f, 0.f);
    }
    __syncthreads();
    const int b = blockIdx.x;
    const int row0 = b << 6;
    const int f = threadIdx.x & 63;
    const int wid = threadIdx.x >> 6;
    const int half = f >> 5;        // edge of the pair
    const int fc = f & 31;          // packed col (cols 2fc, 2fc+1)
    int beg = boff[b], end = boff[b + 1];
    for (int base = beg + wid * 64; base < end; base += 256) {
        int m = end - base; if (m > 64) m = 64;
        uint2 pk = (f < m) ? es[base + f] : make_uint2(0u, 0u);
        u32   me = pk.x;
        float we = __builtin_bit_cast(float, pk.y);
        for (int k = 0; k < m; k += 2) {
            int k0 = k + half;              // lane k0 zeroed if k0 >= m
            u32   mk = __shfl(me, k0, 64);
            float wk = __shfl(we, k0, 64);
            int row = (int)(mk >> 26);
            int s   = (int)(mk & 0x03FFFFFFu);
            u32 x = XW2b[(size_t)s * 32 + fc];
            atomicAdd(&lo[row * 32 + fc], bf_lo(x) * wk);
            atomicAdd(&hi[row * 32 + fc], bf_hi(x) * wk);
        }
    }
    __syncthreads();
    // epilogue: wave per row (f = col 0..63)
    for (int rr = wid; rr < 64; rr += 4) {
        int r = row0 + rr;
        if (r >= N) break;          // wave-uniform
        float a = (f & 1) ? hi[rr * 32 + (f >> 1)] : lo[rr * 32 + (f >> 1)];
        float h = a + b2[f];
        bool s_ = sens[r] != 0;
        bool i_ = ins[r] != 0;
        float pv = prev[(size_t)r * CDIM + f];
        float o = (s_ ? h : pv) + (i_ ? h : 0.f);
        float mm = o;
        #pragma unroll
        for (int off = 32; off > 0; off >>= 1) mm = fmaxf(mm, __shfl_xor(mm, off, 64));
        float e = expf(o - mm);
        float sum = e;
        #pragma unroll
        for (int off = 32; off > 0; off >>= 1) sum += __shfl_xor(sum, off, 64);
        out_lsm[(size_t)r * CDIM + f] = o - mm - logf(sum);
        out_emb[(size_t)r * CDIM + f] = o;
    }
}

extern "C" void kernel_launch(void* const* d_in, const int* in_sizes, int n_in,
                              void* d_out, int out_size, void* d_ws, size_t ws_size,
                              hipStream_t stream) {
    const float* features = (const float*)d_in[0];
    const int*   esrc     = (const int*)d_in[1];
    const int*   edst     = (const int*)d_in[2];
    const float* ew       = (const float*)d_in[3];
    const float* W1       = (const float*)d_in[4];
    const float* b1       = (const float*)d_in[5];
    const float* gamma1   = (const float*)d_in[6];
    const float* beta1    = (const float*)d_in[7];
    const float* mean1    = (const float*)d_in[8];
    const float* var1     = (const float*)d_in[9];
    const float* W2       = (const float*)d_in[10];
    const float* b2       = (const float*)d_in[11];
    const float* prev     = (const float*)d_in[12];
    const int*   sens     = (const int*)d_in[13];
    const int*   ins      = (const int*)d_in[14];

    const int N = in_sizes[0] / F_IN;
    const int E = in_sizes[1];
    const int NB = (N + 63) >> 6;                  // 64-row buckets

    // ---- workspace layout (u32 words) ----
    u32* xw1b  = (u32*)d_ws;                       // N*64  (128 bf16 cols)
    u32* hb    = xw1b + (size_t)N * 64;            // N*64
    u32* xw2b  = hb + (size_t)N * 64;              // N*32
    uint2* es  = (uint2*)(xw2b + (size_t)N * 32);  // E x 8B (8B-aligned: 160N even)
    int* gcount  = (int*)(es + E);                 // NB
    int* boff    = gcount + NB;                    // NB+1
    int* gcursor = boff + NB + 1;                  // NB
    float* scale = (float*)(gcursor + NB);         // 128
    float* shift = scale + HID;                    // 128

    float* out_lsm = (float*)d_out;
    float* out_emb = out_lsm + (size_t)N * CDIM;

    const int nbk = (E + BCHUNK - 1) / BCHUNK;

    // ---- bucket build ----
    hipMemsetAsync(gcount, 0, (size_t)NB * sizeof(int), stream);
    bucket_hist<<<nbk, 256, 0, stream>>>(edst, gcount, E, NB);
    bucket_scan<<<1, 256, 0, stream>>>(gcount, boff, gcursor, NB, E);
    bucket_fill<<<nbk, 256, 0, stream>>>(esrc, edst, ew, gcursor, es, E, NB);
    bn_prep<<<1, 128, 0, stream>>>(b1, gamma1, beta1, mean1, var1, scale, shift);

    // ---- layer 1 ----
    const int ntiles = (N + 127) / 128;
    gemm_xw1<<<ntiles, 256, 0, stream>>>(features, W1, xw1b, N);
    scatter1_kernel<<<NB, 256, 0, stream>>>(xw1b, boff, es, scale, shift, hb, N);
    // ---- layer 2 ----
    gemm_xw2<<<ntiles, 256, 0, stream>>>(hb, W2, xw2b, N);
    scatter2_final<<<NB, 256, 0, stream>>>(xw2b, boff, es, b2, prev, sens, ins,
                                           out_lsm, out_emb, N);
}